// Round 2
// baseline (67.374 us; speedup 1.0000x reference)
//
#include <hip/hip_runtime.h>
#include <stdint.h>

typedef uint32_t u32;
typedef unsigned short u16;

#define LDT 40  // padded LDS row stride (elements) -> 80B rows, 16B-aligned, 2-way bank alias (free)

typedef __bf16 bf16x8 __attribute__((ext_vector_type(8)));
typedef float  f32x4  __attribute__((ext_vector_type(4)));

__device__ __forceinline__ float bf2f(u16 x) {
  union { float f; u32 u; } c; c.u = ((u32)x) << 16; return c.f;
}
__device__ __forceinline__ u16 f2bf(float f) {
  union { float f; u32 u; } c; c.f = f;
  u32 b = c.u;
  return (u16)((b + 0x7FFFu + ((b >> 16) & 1u)) >> 16);
}
__device__ __forceinline__ u32 pk2(float lo, float hi) {
  return (u32)f2bf(lo) | ((u32)f2bf(hi) << 16);
}

// ---------------------------------------------------------------------------
// Kernel 0: transpose+cast Wq/Wk/Wv (f32 [256][256] -> bf16 [n][k]) and
//           Wg1 (f32 [256][24] -> bf16 [32][256] padded)
// ---------------------------------------------------------------------------
__global__ __launch_bounds__(256) void prep_transpose(
    const float* __restrict__ Wq, const float* __restrict__ Wk, const float* __restrict__ Wv,
    const float* __restrict__ Wg1,
    u16* __restrict__ WTq, u16* __restrict__ WTk, u16* __restrict__ WTv,
    u16* __restrict__ Wg1T)
{
  int z = blockIdx.z, bx = blockIdx.x, by = blockIdx.y;
  int x = threadIdx.x, y = threadIdx.y;  // 32 x 8
  __shared__ u16 tile[32][33];
  if (z < 3) {
    const float* W  = (z == 0) ? Wq : (z == 1) ? Wk : Wv;
    u16*         WT = (z == 0) ? WTq : (z == 1) ? WTk : WTv;
    for (int yy = y; yy < 32; yy += 8)
      tile[yy][x] = f2bf(W[(size_t)(by * 32 + yy) * 256 + bx * 32 + x]);
    __syncthreads();
    for (int yy = y; yy < 32; yy += 8)
      WT[(size_t)(bx * 32 + yy) * 256 + by * 32 + x] = tile[x][yy];
  } else {
    if (bx != 0) return;
    for (int yy = y; yy < 32; yy += 8)
      tile[yy][x] = (x < 24) ? f2bf(Wg1[(size_t)(by * 32 + yy) * 24 + x]) : (u16)0;
    __syncthreads();
    for (int yy = y; yy < 32; yy += 8)
      Wg1T[(size_t)yy * 256 + by * 32 + x] = tile[x][yy];
  }
}

// ---------------------------------------------------------------------------
// Kernel 1: q/k/v projections. Y[8192,256] = X @ W + b  (X f32 -> bf16, WT[n][k] bf16)
// 128x128 tile, BK=32, 4 waves in 2x2, each wave 4x4 frags of 16x16x32 MFMA.
// Output bf16 workspace.
// ---------------------------------------------------------------------------
__global__ __launch_bounds__(256) void gemm_qkv(
    const float* __restrict__ Xq, const float* __restrict__ Xk, const float* __restrict__ Xv,
    const u16* __restrict__ WTq, const u16* __restrict__ WTk, const u16* __restrict__ WTv,
    const float* __restrict__ bq, const float* __restrict__ bk, const float* __restrict__ bv,
    u16* __restrict__ Oq, u16* __restrict__ Ok, u16* __restrict__ Ov)
{
  int z = blockIdx.z;
  const float* X    = (z == 0) ? Xq : (z == 1) ? Xk : Xv;
  const u16*   WT   = (z == 0) ? WTq : (z == 1) ? WTk : WTv;
  const float* bias = (z == 0) ? bq : (z == 1) ? bk : bv;
  u16*         O    = (z == 0) ? Oq : (z == 1) ? Ok : Ov;

  int m0 = blockIdx.y * 128;
  int n0 = blockIdx.x * 128;
  int t = threadIdx.x;
  int lane = t & 63, wid = t >> 6;
  int wr = wid >> 1, wc = wid & 1;
  int fr = lane & 15, fg = lane >> 4;

  __shared__ __align__(16) u16 la[128 * LDT];
  __shared__ __align__(16) u16 lb[128 * LDT];

  f32x4 acc[4][4];
#pragma unroll
  for (int i = 0; i < 4; i++)
#pragma unroll
    for (int j = 0; j < 4; j++) acc[i][j] = (f32x4){0.f, 0.f, 0.f, 0.f};

  int sr = t >> 1;         // row within 128-row tile
  int sc = (t & 1) * 16;   // 16-element k chunk

  for (int kt = 0; kt < 256; kt += 32) {
    // A: f32 source -> convert to bf16
    const float4* ga = (const float4*)(X + (size_t)(m0 + sr) * 256 + kt + sc);
    float4 a0 = ga[0], a1 = ga[1], a2 = ga[2], a3 = ga[3];
    // B: already bf16
    const uint4* gb = (const uint4*)(WT + (size_t)(n0 + sr) * 256 + kt + sc);
    uint4 b0 = gb[0], b1 = gb[1];

    uint4 wa0, wa1;
    wa0.x = pk2(a0.x, a0.y); wa0.y = pk2(a0.z, a0.w);
    wa0.z = pk2(a1.x, a1.y); wa0.w = pk2(a1.z, a1.w);
    wa1.x = pk2(a2.x, a2.y); wa1.y = pk2(a2.z, a2.w);
    wa1.z = pk2(a3.x, a3.y); wa1.w = pk2(a3.z, a3.w);

    __syncthreads();
    *(uint4*)&la[sr * LDT + sc]     = wa0;
    *(uint4*)&la[sr * LDT + sc + 8] = wa1;
    *(uint4*)&lb[sr * LDT + sc]     = b0;
    *(uint4*)&lb[sr * LDT + sc + 8] = b1;
    __syncthreads();

    bf16x8 af[4], bfr[4];
#pragma unroll
    for (int s = 0; s < 4; s++)
      af[s] = *(const bf16x8*)&la[(wr * 64 + s * 16 + fr) * LDT + fg * 8];
#pragma unroll
    for (int s = 0; s < 4; s++)
      bfr[s] = *(const bf16x8*)&lb[(wc * 64 + s * 16 + fr) * LDT + fg * 8];
#pragma unroll
    for (int i = 0; i < 4; i++)
#pragma unroll
      for (int j = 0; j < 4; j++)
        acc[i][j] = __builtin_amdgcn_mfma_f32_16x16x32_bf16(af[i], bfr[j], acc[i][j], 0, 0, 0);
  }

#pragma unroll
  for (int i = 0; i < 4; i++) {
    int rowb = m0 + wr * 64 + i * 16 + fg * 4;
#pragma unroll
    for (int j = 0; j < 4; j++) {
      int col = n0 + wc * 64 + j * 16 + fr;
      float bb = bias[col];
#pragma unroll
      for (int r = 0; r < 4; r++)
        O[(size_t)(rowb + r) * 256 + col] = f2bf(acc[i][j][r] + bb);
    }
  }
}

// ---------------------------------------------------------------------------
// Kernel 2: kg1 = k @ Wg1 (f32 [8192][24]); qadj = q @ Wg1 - bg1
// BM=128, 24 cols padded to 32. 4 waves, each 32 rows, 2x2 frags.
// ---------------------------------------------------------------------------
__global__ __launch_bounds__(256) void gemm_g1(
    const u16* __restrict__ Xk, const u16* __restrict__ Xq,
    const u16* __restrict__ Wg1T, const float* __restrict__ bg1,
    float* __restrict__ Okg1, float* __restrict__ Oqadj)
{
  int z = blockIdx.z;
  const u16* X = (z == 0) ? Xk : Xq;
  float*     O = (z == 0) ? Okg1 : Oqadj;

  int m0 = blockIdx.y * 128;
  int t = threadIdx.x;
  int lane = t & 63, wid = t >> 6;
  int fr = lane & 15, fg = lane >> 4;

  __shared__ __align__(16) u16 la[128 * LDT];
  __shared__ __align__(16) u16 lb[32 * LDT];

  f32x4 acc[2][2];
#pragma unroll
  for (int i = 0; i < 2; i++)
#pragma unroll
    for (int j = 0; j < 2; j++) acc[i][j] = (f32x4){0.f, 0.f, 0.f, 0.f};

  int sr = t >> 1;
  int sc = (t & 1) * 16;

  for (int kt = 0; kt < 256; kt += 32) {
    const uint4* ga = (const uint4*)(X + (size_t)(m0 + sr) * 256 + kt + sc);
    uint4 a0 = ga[0], a1 = ga[1];
    uint4 b0, b1;
    if (t < 64) {
      const uint4* gb = (const uint4*)(Wg1T + (size_t)sr * 256 + kt + sc);
      b0 = gb[0]; b1 = gb[1];
    }
    __syncthreads();
    *(uint4*)&la[sr * LDT + sc]     = a0;
    *(uint4*)&la[sr * LDT + sc + 8] = a1;
    if (t < 64) {
      *(uint4*)&lb[sr * LDT + sc]     = b0;
      *(uint4*)&lb[sr * LDT + sc + 8] = b1;
    }
    __syncthreads();

    bf16x8 af[2], bfr[2];
#pragma unroll
    for (int s = 0; s < 2; s++)
      af[s] = *(const bf16x8*)&la[(wid * 32 + s * 16 + fr) * LDT + fg * 8];
#pragma unroll
    for (int s = 0; s < 2; s++)
      bfr[s] = *(const bf16x8*)&lb[(s * 16 + fr) * LDT + fg * 8];
#pragma unroll
    for (int i = 0; i < 2; i++)
#pragma unroll
      for (int j = 0; j < 2; j++)
        acc[i][j] = __builtin_amdgcn_mfma_f32_16x16x32_bf16(af[i], bfr[j], acc[i][j], 0, 0, 0);
  }

#pragma unroll
  for (int i = 0; i < 2; i++) {
    int rowb = m0 + wid * 32 + i * 16 + fg * 4;
#pragma unroll
    for (int j = 0; j < 2; j++) {
      int col = j * 16 + fr;
      if (col < 24) {
        float sub = (z == 1) ? bg1[col] : 0.f;
#pragma unroll
        for (int r = 0; r < 4; r++)
          O[(size_t)(rowb + r) * 24 + col] = acc[i][j][r] - sub;
      }
    }
  }
}

// ---------------------------------------------------------------------------
// Kernel 3: per-point edge/attention fusion. One 256-thread block per point.
// ---------------------------------------------------------------------------
__global__ __launch_bounds__(256) void edge_attn(
    const u16* __restrict__ qb, const u16* __restrict__ kb, const u16* __restrict__ vb,
    const float* __restrict__ kg1, const float* __restrict__ qadj,
    const int* __restrict__ ip, const float* __restrict__ raw,
    const float* __restrict__ rpe, const float* __restrict__ wg2b,
    const float* __restrict__ bg2b, float* __restrict__ out)
{
  int p = blockIdx.x, t = threadIdx.x;
  __shared__ __align__(16) u16   q_s[256];
  __shared__            int   idx_s[32];
  __shared__            float sh_s[32][3];
  __shared__            float qadj_s[24];
  __shared__            float bg2_s[24];
  __shared__            float wg2_s[576];
  __shared__ __align__(16) float kg1_s[32 * 24];
  __shared__            float pre_s[32][24];
  __shared__            float logit_s[32][8];
  __shared__            float att_s[32][8];
  __shared__            float m_s[8], is_s[8];

  q_s[t] = qb[(size_t)p * 256 + t];
  if (t < 32) idx_s[t] = ip[(size_t)p * 32 + t];
  if (t >= 32 && t < 56) qadj_s[t - 32] = qadj[(size_t)p * 24 + (t - 32)];
  if (t >= 64 && t < 88) bg2_s[t - 64] = bg2b[t - 64];
  if (t < 192) {
    wg2_s[t]       = wg2b[t];
    wg2_s[t + 192] = wg2b[t + 192];
    wg2_s[t + 384] = wg2b[t + 384];
  }
  if (t >= 96 && t < 128) {
    int n = t - 96;
    float x  = rpe[((size_t)p * 32 + n) * 3 + 0];
    float y  = rpe[((size_t)p * 32 + n) * 3 + 1];
    float zz = rpe[((size_t)p * 32 + n) * 3 + 2];
    float rl = sqrtf(x * x + y * y + zz * zz);
    float inv = 1.f / fmaxf(rl, 1e-12f);
    float tt = (rl - 0.001f) * 250.f;
    tt = fminf(fmaxf(tt, 0.f), 1.f);
    float cut = 0.5f * (1.f - cosf(tt * 3.14159265358979f));
    float s3c = 1.7320508075688772f * inv * cut;
    sh_s[n][0] = x * s3c; sh_s[n][1] = y * s3c; sh_s[n][2] = zz * s3c;
  }
  __syncthreads();

  if (t < 192) {  // stage gathered kg1 rows: 32 rows x 6 float4
    int n = t / 6, f = t % 6;
    const float4* kp = (const float4*)(kg1 + (size_t)idx_s[n] * 24);
    *(float4*)&kg1_s[n * 24 + f * 4] = kp[f];
  }
  __syncthreads();

  {  // pre-activation + relu
    int n = t >> 3, jj = t & 7;
#pragma unroll
    for (int c = 0; c < 3; c++) {
      int i = jj * 3 + c;
      pre_s[n][i] = fmaxf(kg1_s[n * 24 + i] - qadj_s[i], 0.f);
    }
  }
  __syncthreads();

  {  // logits: thread = (n, h)
    int n = t >> 3, h = t & 7;
    const uint4* kr = (const uint4*)(kb + (size_t)idx_s[n] * 256 + h * 32);
    const uint4* qr = (const uint4*)(q_s + h * 32);
    float dot = 0.f;
#pragma unroll
    for (int c = 0; c < 4; c++) {
      uint4 kw = kr[c], qw = qr[c];
#pragma unroll
      for (int e = 0; e < 4; e++) {
        u32 kwe = (&kw.x)[e], qwe = (&qw.x)[e];
        float klo = bf2f((u16)(kwe & 0xFFFF)), khi = bf2f((u16)(kwe >> 16));
        float qlo = bf2f((u16)(qwe & 0xFFFF)), qhi = bf2f((u16)(qwe >> 16));
        dot += klo * qlo + khi * qhi;
      }
    }
    float g0 = bg2_s[h * 3 + 0], g1v = bg2_s[h * 3 + 1], g2v = bg2_s[h * 3 + 2];
#pragma unroll
    for (int i = 0; i < 24; i++) {
      float pr = pre_s[n][i];
      int b = i * 24 + h * 3;
      g0  += pr * wg2_s[b + 0];
      g1v += pr * wg2_s[b + 1];
      g2v += pr * wg2_s[b + 2];
    }
    float pos = g0 * sh_s[n][0] + g1v * sh_s[n][1] + g2v * sh_s[n][2];
    float rw = raw[(size_t)p * 256 + t];
    logit_s[n][h] = (dot + pos + rw) * 0.17677669529663687f;
  }
  __syncthreads();

  if (t < 8) {
    float m = -1e30f;
    for (int n = 0; n < 32; n++) m = fmaxf(m, logit_s[n][t]);
    float s = 0.f;
    for (int n = 0; n < 32; n++) s += __expf(logit_s[n][t] - m);
    m_s[t] = m; is_s[t] = 1.f / s;
  }
  __syncthreads();

  {
    int n = t >> 3, h = t & 7;
    att_s[n][h] = __expf(logit_s[n][h] - m_s[h]) * is_s[h];
  }
  __syncthreads();

  {
    int h = t >> 5;
    float acc = 0.f;
#pragma unroll
    for (int n = 0; n < 32; n++)
      acc += att_s[n][h] * bf2f(vb[(size_t)idx_s[n] * 256 + t]);
    out[(size_t)p * 256 + t] = acc;
  }
}

// ---------------------------------------------------------------------------
extern "C" void kernel_launch(void* const* d_in, const int* in_sizes, int n_in,
                              void* d_out, int out_size, void* d_ws, size_t ws_size,
                              hipStream_t stream) {
  const float* query = (const float*)d_in[0];
  const float* key_x = (const float*)d_in[1];
  const float* value = (const float*)d_in[2];
  const int*   index_pair = (const int*)d_in[3];
  const float* raw  = (const float*)d_in[4];
  const float* rpe  = (const float*)d_in[5];
  const float* Wq = (const float*)d_in[6];
  const float* bq = (const float*)d_in[7];
  const float* Wk = (const float*)d_in[8];
  const float* bk = (const float*)d_in[9];
  const float* Wv = (const float*)d_in[10];
  const float* bv = (const float*)d_in[11];
  const float* Wg1 = (const float*)d_in[12];
  const float* bg1 = (const float*)d_in[13];
  const float* Wg2 = (const float*)d_in[14];
  const float* bg2 = (const float*)d_in[15];
  float* out = (float*)d_out;

  char* ws = (char*)d_ws;
  u16*   qbuf = (u16*)(ws);                          // 4MB  [8192][256] bf16
  u16*   kbuf = (u16*)(ws + (4u << 20));             // 4MB
  u16*   vbuf = (u16*)(ws + (8u << 20));             // 4MB
  float* kg1  = (float*)(ws + (12u << 20));          // 768KB [8192][24] f32
  float* qadj = (float*)(ws + (12u << 20) + 786432); // 768KB
  u16*   WTq  = (u16*)(ws + (12u << 20) + 2 * 786432);
  u16*   WTk  = WTq + 65536;
  u16*   WTv  = WTk + 65536;
  u16*   Wg1T = WTv + 65536;                         // [32][256] bf16

  prep_transpose<<<dim3(8, 8, 4), dim3(32, 8, 1), 0, stream>>>(
      Wq, Wk, Wv, Wg1, WTq, WTk, WTv, Wg1T);
  gemm_qkv<<<dim3(2, 64, 3), 256, 0, stream>>>(
      query, key_x, value, WTq, WTk, WTv, bq, bk, bv, qbuf, kbuf, vbuf);
  gemm_g1<<<dim3(1, 64, 2), 256, 0, stream>>>(
      kbuf, qbuf, Wg1T, bg1, kg1, qadj);
  edge_attn<<<8192, 256, 0, stream>>>(
      qbuf, kbuf, vbuf, kg1, qadj, index_pair, raw, rpe, Wg2, bg2, out);
}